// Round 15
// baseline (112.132 us; speedup 1.0000x reference)
//
#include <hip/hip_runtime.h>
#include <hip/hip_bf16.h>

#define NROW 4096
#define KDIM 2048
#define ROWB (KDIM * 2)     // bytes per Xb row
#define BTM 128             // job tile rows (A)
#define BTN 64              // job tile cols (B)  -- half-jobs for balance
#define NB (NROW / BTM)     // 32 block-rows; triangle jobs = 528; grid = 1056
#define BK 32               // k-tile depth (64 bytes)
#define NT (KDIM / BK)      // 64 k-tiles
#define KTBUF 12288         // per k-tile: A 8 KB + B 4 KB
#define AB_OFF 8192
#define PHI(r) ((((r) >> 1) & 3) << 4)   // verified 0 bank conflicts (r3/r8/r9)

typedef __attribute__((ext_vector_type(8))) short bf16x8;
typedef __attribute__((ext_vector_type(4))) float f32x4;
typedef __attribute__((ext_vector_type(4))) unsigned short u16x4;

#define MFMA16(a, b, c) __builtin_amdgcn_mfma_f32_16x16x32_bf16((a), (b), (c), 0, 0, 0)

__device__ __forceinline__ unsigned short f2bf(float x) {
    unsigned u = __float_as_uint(x);
    unsigned r = (u + 0x7FFFu + ((u >> 16) & 1u)) >> 16;
    return (unsigned short)r;
}
__device__ __forceinline__ float bf2f(unsigned short b) {
    return __uint_as_float(((unsigned)b) << 16);
}

// Kernel 1: fp32 -> bf16 copy + row sum-of-squares from the bf16 values.
// Also folds the accumulator-init (first 16 blocks) and out-zeroing.
__global__ __launch_bounds__(256) void k_convert(const float* __restrict__ X,
                                                 unsigned short* __restrict__ Xb,
                                                 float* __restrict__ sqv,
                                                 unsigned* __restrict__ hp,
                                                 unsigned* __restrict__ hn,
                                                 unsigned* __restrict__ mor,
                                                 unsigned* __restrict__ mir,
                                                 float* __restrict__ out) {
    const int row = blockIdx.x;
    const int t = threadIdx.x;
    if (row < 16) {  // init per-row accumulators (d^2-space)
        const int i = row * 256 + t;
        hp[i] = 0u;
        hn[i] = 0x7F800000u;
        mor[i] = 0u;
        mir[i] = 0x7F800000u;
        if (i == 0) out[0] = 0.f;
    }
    const float4* xr = (const float4*)(X + (size_t)row * KDIM);
    unsigned short* br = Xb + (size_t)row * KDIM;
    float acc = 0.f;
#pragma unroll
    for (int it = 0; it < 2; ++it) {
        int idx = t * 2 + it;
        float4 v = xr[idx];
        u16x4 b;
        b.x = f2bf(v.x); b.y = f2bf(v.y); b.z = f2bf(v.z); b.w = f2bf(v.w);
        float f0 = bf2f(b.x), f1 = bf2f(b.y), f2 = bf2f(b.z), f3 = bf2f(b.w);
        acc += f0 * f0 + f1 * f1 + f2 * f2 + f3 * f3;
        *(u16x4*)(br + idx * 4) = b;
    }
#pragma unroll
    for (int s = 32; s > 0; s >>= 1) acc += __shfl_xor(acc, s);
    __shared__ float red[4];
    const int lane = t & 63, wid = t >> 6;
    if (lane == 0) red[wid] = acc;
    __syncthreads();
    if (t == 0) sqv[row] = red[0] + red[1] + red[2] + red[3];
}

// Kernel 2: 128x64 HALF-JOB Gram GEMM over the upper triangle.
// 1056 jobs (= 528 triangle jobs x 2 N-halves) of equal size -> 4.125
// jobs/CU at 4-blocks/CU capacity: grid-quantization imbalance drops from
// R9's 1.45x (528 jobs @ 2.06/CU) to ~1.08x. Per-wave workload is
// byte-identical to R9's best: 64x64 output, 16 MFMA + 8 ds_read_b128 per
// K-tile. Block = 128 threads (2 waves: wave w owns A rows w*64..+64).
// Minimal-sync K-step (r8): [vmcnt(6); s_barrier; reads; stage t+2; MFMA].
// 3 LDS buffers (36 KiB), depth-2 staging, vmcnt never drains mid-loop,
// reads issued before the LDS-writing gloads (alias-wait avoidance).
// Source-side XOR swizzle (rule #21). Epilogue in d^2 space, row+col side
// (dist/masks symmetric, max/min idempotent).
__global__ __launch_bounds__(128, 2) void k_gemm(const unsigned short* __restrict__ Xb,
                                                 const float* __restrict__ sqv,
                                                 const int* __restrict__ ta,
                                                 const int* __restrict__ tb,
                                                 unsigned int* __restrict__ hp,
                                                 unsigned int* __restrict__ hn,
                                                 unsigned int* __restrict__ mor,
                                                 unsigned int* __restrict__ mir) {
    __shared__ char lds[3 * KTBUF];  // 36 KiB
    // job decode: full triangle job j = blockIdx.x>>1, N-half h = &1
    int rem = blockIdx.x >> 1;
    const int h = blockIdx.x & 1;
    int bi = 0;
    while (rem >= NB - bi) { rem -= NB - bi; ++bi; }
    const int bj = bi + rem;

    const int t = threadIdx.x;
    const int lane = t & 63;
    const int w = t >> 6;        // wave 0..1: A-row half
    const int l15 = lane & 15;
    const int kg16 = (lane >> 4) * 16;  // k-group 16B slot within 64B row
    const char* xbase = (const char*)Xb;

    // swizzle is lane-constant for frag rows (offsets are multiples of 16)
    const int swz = ((l15 >> 1) & 3) << 4;
    const int akbase = (w * 64 + l15) * 64 + (kg16 ^ swz);
    const int bkbase = AB_OFF + l15 * 64 + (kg16 ^ swz);

    f32x4 acc[4][4] = {};

    // Stage k-tile tt into buffer sb3: 6 gload_lds per thread
    // (A: 4 chunks of 32 rows; B: 2 chunks of 32 rows).
    // Thread t -> row c*32 + (t>>2), 16B col t&3. Wave-linear LDS dest;
    // swizzle on the global source column.
#define STAGE(tt, sb3)                                                        \
    do {                                                                      \
        _Pragma("unroll")                                                     \
        for (int c_ = 0; c_ < 4; ++c_) {                                      \
            const int row_ = c_ * 32 + (t >> 2);                              \
            const int gr_ = bi * BTM + row_;                                  \
            const char* gsrc_ = xbase + (size_t)gr_ * ROWB +                  \
                                (size_t)(tt) * 64 +                           \
                                (((t & 3) * 16) ^ PHI(row_));                 \
            char* ldst_ = lds + (sb3) * KTBUF + row_ * 64 + (t & 3) * 16;     \
            __builtin_amdgcn_global_load_lds(                                 \
                (const __attribute__((address_space(1))) void*)gsrc_,         \
                (__attribute__((address_space(3))) void*)ldst_, 16, 0, 0);    \
        }                                                                     \
        _Pragma("unroll")                                                     \
        for (int c_ = 0; c_ < 2; ++c_) {                                      \
            const int row_ = c_ * 32 + (t >> 2);                              \
            const int gr_ = bj * BTM + h * BTN + row_;                        \
            const char* gsrc_ = xbase + (size_t)gr_ * ROWB +                  \
                                (size_t)(tt) * 64 +                           \
                                (((t & 3) * 16) ^ PHI(row_));                 \
            char* ldst_ = lds + (sb3) * KTBUF + AB_OFF + row_ * 64 +          \
                          (t & 3) * 16;                                       \
            __builtin_amdgcn_global_load_lds(                                 \
                (const __attribute__((address_space(1))) void*)gsrc_,         \
                (__attribute__((address_space(3))) void*)ldst_, 16, 0, 0);    \
        }                                                                     \
    } while (0)

    // prologue: tiles 0 -> buf0, 1 -> buf1 (12 loads/thread outstanding)
    STAGE(0, 0);
    STAGE(1, 1);

    int r3 = 0, s3 = 2;  // read buffer, stage buffer (t+2)
    for (int tk = 0; tk < NT; ++tk) {
        if (tk < NT - 1)
            asm volatile("s_waitcnt vmcnt(6)" ::: "memory");  // buf r3 resident
        else
            asm volatile("s_waitcnt vmcnt(0)" ::: "memory");
        __builtin_amdgcn_s_barrier();

        const char* buf = lds + r3 * KTBUF;
        // ---- all fragment reads first (before any LDS-writing vmem)
        bf16x8 af[4], bfr[4];
#pragma unroll
        for (int m = 0; m < 4; ++m)
            af[m] = *(const bf16x8*)(buf + akbase + m * 1024);
#pragma unroll
        for (int n = 0; n < 4; ++n)
            bfr[n] = *(const bf16x8*)(buf + bkbase + n * 1024);

        // ---- stage tile tk+2 (WAR-safe: that buffer's reads finished
        // before the barrier above)
        if (tk + 2 < NT) STAGE(tk + 2, s3);

        // ---- 16 MFMA; compiler inserts fine-grained lgkm waits
#pragma unroll
        for (int m = 0; m < 4; ++m)
#pragma unroll
            for (int n = 0; n < 4; ++n)
                acc[m][n] = MFMA16(af[m], bfr[n], acc[m][n]);

        r3 = (r3 == 2) ? 0 : r3 + 1;
        s3 = (s3 == 2) ? 0 : s3 + 1;
    }
#undef STAGE

    // ---- epilogue: d^2 + masks + row/col reductions (d^2-space) ----
    float sqj[4];
    int taj[4], tbj[4];
#pragma unroll
    for (int n = 0; n < 4; ++n) {
        int j = bj * BTM + h * BTN + n * 16 + l15;
        sqj[n] = sqv[j];
        taj[n] = ta[j];
        tbj[n] = tb[j];
    }
    const float INF = __uint_as_float(0x7F800000u);

    // column-side accumulators (per n, reduced over m/reg in-thread)
    float chp[4], chn[4], cmo[4], cmi[4];
#pragma unroll
    for (int n = 0; n < 4; ++n) {
        chp[n] = 0.f; chn[n] = INF; cmo[n] = 0.f; cmi[n] = INF;
    }

#pragma unroll
    for (int m = 0; m < 4; ++m) {
#pragma unroll
        for (int reg = 0; reg < 4; ++reg) {
            const int i = bi * BTM + w * 64 + m * 16 + (lane >> 4) * 4 + reg;
            const float sqi = sqv[i];
            const int tai = ta[i], tbi = tb[i];
            float vhp = 0.f, vhn = INF, vmo = 0.f, vmi = INF;
#pragma unroll
            for (int n = 0; n < 4; ++n) {
                float d2 = fmaxf(sqi + sqj[n] - 2.f * acc[m][n][reg], 1e-12f);
                bool ma = (tai == taj[n]), mb = (tbi == tbj[n]);
                if (ma && mb) {
                    vhp = fmaxf(vhp, d2);
                    chp[n] = fmaxf(chp[n], d2);
                } else if (ma != mb) {
                    vmo = fmaxf(vmo, d2);
                    vmi = fminf(vmi, d2);
                    cmo[n] = fmaxf(cmo[n], d2);
                    cmi[n] = fminf(cmi[n], d2);
                } else {
                    vhn = fminf(vhn, d2);
                    chn[n] = fminf(chn[n], d2);
                }
            }
#pragma unroll
            for (int s = 1; s < 16; s <<= 1) {
                vhp = fmaxf(vhp, __shfl_xor(vhp, s, 16));
                vhn = fminf(vhn, __shfl_xor(vhn, s, 16));
                vmo = fmaxf(vmo, __shfl_xor(vmo, s, 16));
                vmi = fminf(vmi, __shfl_xor(vmi, s, 16));
            }
            if (l15 == 0) {
                if (vhp > 0.f) atomicMax(&hp[i], __float_as_uint(vhp));
                if (vhn < INF) atomicMin(&hn[i], __float_as_uint(vhn));
                if (vmo > 0.f) {
                    atomicMax(&mor[i], __float_as_uint(vmo));
                    atomicMin(&mir[i], __float_as_uint(vmi));
                }
            }
        }
    }

    if (bi != bj) {
        // column-side: reduce across the 4 row-groups (lane>>4) via xor-16/32;
        // each wave covers its own 64 A-rows, both atomically merge into j.
#pragma unroll
        for (int n = 0; n < 4; ++n) {
            float a = chp[n], b = chn[n], c = cmo[n], d = cmi[n];
            a = fmaxf(a, __shfl_xor(a, 16)); a = fmaxf(a, __shfl_xor(a, 32));
            b = fminf(b, __shfl_xor(b, 16)); b = fminf(b, __shfl_xor(b, 32));
            c = fmaxf(c, __shfl_xor(c, 16)); c = fmaxf(c, __shfl_xor(c, 32));
            d = fminf(d, __shfl_xor(d, 16)); d = fminf(d, __shfl_xor(d, 32));
            if (lane < 16) {
                const int j = bj * BTM + h * BTN + n * 16 + lane;
                if (a > 0.f) atomicMax(&hp[j], __float_as_uint(a));
                if (b < INF) atomicMin(&hn[j], __float_as_uint(b));
                if (c > 0.f) {
                    atomicMax(&mor[j], __float_as_uint(c));
                    atomicMin(&mir[j], __float_as_uint(d));
                }
            }
        }
    }
}

// Kernel 3: final scalar loss (sqrt applied here; mor!=0 is the or-flag).
__global__ __launch_bounds__(256) void k_final(const unsigned* __restrict__ hp,
                                               const unsigned* __restrict__ hn,
                                               const unsigned* __restrict__ mor,
                                               const unsigned* __restrict__ mir,
                                               const int* __restrict__ epoch_p,
                                               float* __restrict__ out) {
    const int t = threadIdx.x;
    const int i = blockIdx.x * 256 + t;
    const bool eok = (*epoch_p > 50);
    const unsigned morb = mor[i];
    float fhp = sqrtf(__uint_as_float(hp[i]));
    float fhn = sqrtf(__uint_as_float(hn[i]));
    bool use_or = (morb != 0u) && eok;
    float sp = use_or ? sqrtf(__uint_as_float(morb)) : fhp;
    float sn = use_or ? sqrtf(__uint_as_float(mir[i])) : fhn;
    float s = fmaxf(0.f, fhp - fhn + 0.3f) + fmaxf(0.f, sp - fhn + 0.3f) +
              fmaxf(0.f, fhp - sn + 0.3f);
#pragma unroll
    for (int sh = 32; sh > 0; sh >>= 1) s += __shfl_xor(s, sh);
    __shared__ float red[4];
    const int lane = t & 63, wid = t >> 6;
    if (lane == 0) red[wid] = s;
    __syncthreads();
    if (t == 0)
        atomicAdd(out, (red[0] + red[1] + red[2] + red[3]) * (1.f / 4096.f));
}

extern "C" void kernel_launch(void* const* d_in, const int* in_sizes, int n_in,
                              void* d_out, int out_size, void* d_ws, size_t ws_size,
                              hipStream_t stream) {
    const float* X = (const float*)d_in[0];
    const int* ta = (const int*)d_in[1];
    const int* tb = (const int*)d_in[2];
    const int* epoch_p = (const int*)d_in[4];
    float* out = (float*)d_out;

    char* ws = (char*)d_ws;
    unsigned short* Xb = (unsigned short*)ws;  // 16 MB bf16 copy
    size_t off = (size_t)NROW * KDIM * sizeof(unsigned short);
    float* sqv = (float*)(ws + off); off += (size_t)NROW * 4;
    unsigned* hp = (unsigned*)(ws + off); off += (size_t)NROW * 4;
    unsigned* hn = (unsigned*)(ws + off); off += (size_t)NROW * 4;
    unsigned* mor = (unsigned*)(ws + off); off += (size_t)NROW * 4;
    unsigned* mir = (unsigned*)(ws + off); off += (size_t)NROW * 4;

    k_convert<<<NROW, 256, 0, stream>>>(X, Xb, sqv, hp, hn, mor, mir, out);
    k_gemm<<<NB * (NB + 1), 128, 0, stream>>>(Xb, sqv, ta, tb,
                                              hp, hn, mor, mir);
    k_final<<<NROW / 256, 256, 0, stream>>>(hp, hn, mor, mir, epoch_p, out);
}

// Round 16
// 90.361 us; speedup vs baseline: 1.2409x; 1.2409x over previous
//
#include <hip/hip_runtime.h>
#include <hip/hip_bf16.h>

#define NROW 4096
#define KDIM 2048
#define ROWB (KDIM * 2)     // bytes per Xb row
#define BT 128              // block tile (M = N)
#define NB (NROW / BT)      // 32 block-rows; triangle grid = 528
#define BK 32               // k-tile depth (64 bytes)
#define NT (KDIM / BK)      // 64 k-tiles
#define KTBUF 16384         // per k-tile: A 8 KB + B 8 KB
#define AB_OFF 8192
#define PHI(r) ((((r) >> 1) & 3) << 4)   // verified 0 bank conflicts (r3/r8/r9)

typedef __attribute__((ext_vector_type(8))) short bf16x8;
typedef __attribute__((ext_vector_type(4))) float f32x4;
typedef __attribute__((ext_vector_type(4))) unsigned short u16x4;

#define MFMA16(a, b, c) __builtin_amdgcn_mfma_f32_16x16x32_bf16((a), (b), (c), 0, 0, 0)

__device__ __forceinline__ unsigned short f2bf(float x) {
    unsigned u = __float_as_uint(x);
    unsigned r = (u + 0x7FFFu + ((u >> 16) & 1u)) >> 16;
    return (unsigned short)r;
}
__device__ __forceinline__ float bf2f(unsigned short b) {
    return __uint_as_float(((unsigned)b) << 16);
}

// Kernel 1: fp32 -> bf16 copy + row sum-of-squares from the bf16 values.
// Folds the accumulator-init (first 16 blocks) and out-zeroing (validated
// in r10-r14; saves one dispatch vs r9).
__global__ __launch_bounds__(256) void k_convert(const float* __restrict__ X,
                                                 unsigned short* __restrict__ Xb,
                                                 float* __restrict__ sqv,
                                                 unsigned* __restrict__ hp,
                                                 unsigned* __restrict__ hn,
                                                 unsigned* __restrict__ mor,
                                                 unsigned* __restrict__ mir,
                                                 float* __restrict__ out) {
    const int row = blockIdx.x;
    const int t = threadIdx.x;
    if (row < 16) {  // init per-row accumulators (d^2-space)
        const int i = row * 256 + t;
        hp[i] = 0u;
        hn[i] = 0x7F800000u;
        mor[i] = 0u;
        mir[i] = 0x7F800000u;
        if (i == 0) out[0] = 0.f;
    }
    const float4* xr = (const float4*)(X + (size_t)row * KDIM);
    unsigned short* br = Xb + (size_t)row * KDIM;
    float acc = 0.f;
#pragma unroll
    for (int it = 0; it < 2; ++it) {
        int idx = t * 2 + it;
        float4 v = xr[idx];
        u16x4 b;
        b.x = f2bf(v.x); b.y = f2bf(v.y); b.z = f2bf(v.z); b.w = f2bf(v.w);
        float f0 = bf2f(b.x), f1 = bf2f(b.y), f2 = bf2f(b.z), f3 = bf2f(b.w);
        acc += f0 * f0 + f1 * f1 + f2 * f2 + f3 * f3;
        *(u16x4*)(br + idx * 4) = b;
    }
#pragma unroll
    for (int s = 32; s > 0; s >>= 1) acc += __shfl_xor(acc, s);
    __shared__ float red[4];
    const int lane = t & 63, wid = t >> 6;
    if (lane == 0) red[wid] = acc;
    __syncthreads();
    if (t == 0) sqv[row] = red[0] + red[1] + red[2] + red[3];
}

// Kernel 2 (r9 optimum, byte-identical): 128x128-tile Gram GEMM,
// UPPER-TRIANGLE grid (528 blocks), minimal-sync K-step, 48 KiB LDS
// (3 buffers) -> 3 blocks/CU capacity. Per K-tile:
//   [vmcnt(4); s_barrier; 8 ds_read_b128; stage t+2; 16 MFMA]
// Reads issued before the LDS-writing gload_lds (alias-wait avoidance).
// dist/masks symmetric + max/min idempotent -> off-diagonal blocks feed
// both row i and row j reductions, all in d^2 space (sqrt deferred).
__global__ __launch_bounds__(256, 3) void k_gemm(const unsigned short* __restrict__ Xb,
                                                 const float* __restrict__ sqv,
                                                 const int* __restrict__ ta,
                                                 const int* __restrict__ tb,
                                                 unsigned int* __restrict__ hp,
                                                 unsigned int* __restrict__ hn,
                                                 unsigned int* __restrict__ mor,
                                                 unsigned int* __restrict__ mir) {
    __shared__ char lds[3 * KTBUF];  // 48 KiB
    // triangle decode: block-row bi has (NB - bi) blocks, bj in [bi, NB)
    int rem = blockIdx.x;
    int bi = 0;
    while (rem >= NB - bi) { rem -= NB - bi; ++bi; }
    const int bj = bi + rem;

    const int t = threadIdx.x;
    const int lane = t & 63;
    const int w = t >> 6;        // wave 0..3
    const int wm = w >> 1;       // 0..1  (64-row half of A)
    const int wn = w & 1;        // 0..1  (64-col half of B)
    const int l15 = lane & 15;
    const int kg16 = (lane >> 4) * 16;  // k-group 16B slot within 64B row
    const char* xbase = (const char*)Xb;

    // swizzle is lane-constant for frag rows (offsets are multiples of 16)
    const int swz = ((l15 >> 1) & 3) << 4;
    const int akbase = (wm * 64 + l15) * 64 + (kg16 ^ swz);
    const int bkbase = AB_OFF + (wn * 64 + l15) * 64 + (kg16 ^ swz);

    f32x4 acc[4][4] = {};

    // Stage k-tile tt into buffer sb3: 4 gload_lds per thread (A q0,q1 +
    // B q0,q1). Wave-linear LDS dest; swizzle on the global source column.
#define STAGE(tt, sb3)                                                        \
    do {                                                                      \
        _Pragma("unroll")                                                     \
        for (int isb_ = 0; isb_ < 2; ++isb_) {                                \
            _Pragma("unroll")                                                 \
            for (int q_ = 0; q_ < 2; ++q_) {                                  \
                const int row_ = q_ * 64 + (t >> 2);                          \
                const int gr_ = (isb_ ? bj : bi) * BT + row_;                 \
                const char* gsrc_ = xbase + (size_t)gr_ * ROWB +              \
                                    (size_t)(tt) * 64 +                       \
                                    (((t & 3) * 16) ^ PHI(row_));             \
                char* ldst_ = lds + (sb3) * KTBUF + isb_ * AB_OFF +           \
                              row_ * 64 + (t & 3) * 16;                       \
                __builtin_amdgcn_global_load_lds(                             \
                    (const __attribute__((address_space(1))) void*)gsrc_,     \
                    (__attribute__((address_space(3))) void*)ldst_, 16, 0, 0);\
            }                                                                 \
        }                                                                     \
    } while (0)

    // prologue: tiles 0 -> buf0, 1 -> buf1 (8 loads/thread outstanding)
    STAGE(0, 0);
    STAGE(1, 1);

    int r3 = 0, s3 = 2;  // read buffer, stage buffer (t+2)
    for (int tk = 0; tk < NT; ++tk) {
        if (tk < NT - 1)
            asm volatile("s_waitcnt vmcnt(4)" ::: "memory");  // buf r3 resident
        else
            asm volatile("s_waitcnt vmcnt(0)" ::: "memory");
        __builtin_amdgcn_s_barrier();

        const char* buf = lds + r3 * KTBUF;
        // ---- all fragment reads first (before any LDS-writing vmem)
        bf16x8 af[4], bfr[4];
#pragma unroll
        for (int m = 0; m < 4; ++m)
            af[m] = *(const bf16x8*)(buf + akbase + m * 1024);
#pragma unroll
        for (int n = 0; n < 4; ++n)
            bfr[n] = *(const bf16x8*)(buf + bkbase + n * 1024);

        // ---- stage tile tk+2 (WAR-safe: that buffer's reads finished
        // before the barrier above)
        if (tk + 2 < NT) STAGE(tk + 2, s3);

        // ---- 16 MFMA; compiler inserts fine-grained lgkm waits
#pragma unroll
        for (int m = 0; m < 4; ++m)
#pragma unroll
            for (int n = 0; n < 4; ++n)
                acc[m][n] = MFMA16(af[m], bfr[n], acc[m][n]);

        r3 = (r3 == 2) ? 0 : r3 + 1;
        s3 = (s3 == 2) ? 0 : s3 + 1;
    }
#undef STAGE

    // ---- epilogue: d^2 + masks + row/col reductions (d^2-space) ----
    float sqj[4];
    int taj[4], tbj[4];
#pragma unroll
    for (int n = 0; n < 4; ++n) {
        int j = bj * BT + wn * 64 + n * 16 + l15;
        sqj[n] = sqv[j];
        taj[n] = ta[j];
        tbj[n] = tb[j];
    }
    const float INF = __uint_as_float(0x7F800000u);

    // column-side accumulators (per n, reduced over m/reg in-thread)
    float chp[4], chn[4], cmo[4], cmi[4];
#pragma unroll
    for (int n = 0; n < 4; ++n) {
        chp[n] = 0.f; chn[n] = INF; cmo[n] = 0.f; cmi[n] = INF;
    }

#pragma unroll
    for (int m = 0; m < 4; ++m) {
#pragma unroll
        for (int reg = 0; reg < 4; ++reg) {
            const int i = bi * BT + wm * 64 + m * 16 + (lane >> 4) * 4 + reg;
            const float sqi = sqv[i];
            const int tai = ta[i], tbi = tb[i];
            float vhp = 0.f, vhn = INF, vmo = 0.f, vmi = INF;
#pragma unroll
            for (int n = 0; n < 4; ++n) {
                float d2 = fmaxf(sqi + sqj[n] - 2.f * acc[m][n][reg], 1e-12f);
                bool ma = (tai == taj[n]), mb = (tbi == tbj[n]);
                if (ma && mb) {
                    vhp = fmaxf(vhp, d2);
                    chp[n] = fmaxf(chp[n], d2);
                } else if (ma != mb) {
                    vmo = fmaxf(vmo, d2);
                    vmi = fminf(vmi, d2);
                    cmo[n] = fmaxf(cmo[n], d2);
                    cmi[n] = fminf(cmi[n], d2);
                } else {
                    vhn = fminf(vhn, d2);
                    chn[n] = fminf(chn[n], d2);
                }
            }
#pragma unroll
            for (int s = 1; s < 16; s <<= 1) {
                vhp = fmaxf(vhp, __shfl_xor(vhp, s, 16));
                vhn = fminf(vhn, __shfl_xor(vhn, s, 16));
                vmo = fmaxf(vmo, __shfl_xor(vmo, s, 16));
                vmi = fminf(vmi, __shfl_xor(vmi, s, 16));
            }
            if (l15 == 0) {
                if (vhp > 0.f) atomicMax(&hp[i], __float_as_uint(vhp));
                if (vhn < INF) atomicMin(&hn[i], __float_as_uint(vhn));
                if (vmo > 0.f) {
                    atomicMax(&mor[i], __float_as_uint(vmo));
                    atomicMin(&mir[i], __float_as_uint(vmi));
                }
            }
        }
    }

    if (bi != bj) {
        // column-side: reduce across the 4 row-groups (lane>>4) via xor-16/32
#pragma unroll
        for (int n = 0; n < 4; ++n) {
            float a = chp[n], b = chn[n], c = cmo[n], d = cmi[n];
            a = fmaxf(a, __shfl_xor(a, 16)); a = fmaxf(a, __shfl_xor(a, 32));
            b = fminf(b, __shfl_xor(b, 16)); b = fminf(b, __shfl_xor(b, 32));
            c = fmaxf(c, __shfl_xor(c, 16)); c = fmaxf(c, __shfl_xor(c, 32));
            d = fminf(d, __shfl_xor(d, 16)); d = fminf(d, __shfl_xor(d, 32));
            if (lane < 16) {
                const int j = bj * BT + wn * 64 + n * 16 + lane;
                if (a > 0.f) atomicMax(&hp[j], __float_as_uint(a));
                if (b < INF) atomicMin(&hn[j], __float_as_uint(b));
                if (c > 0.f) {
                    atomicMax(&mor[j], __float_as_uint(c));
                    atomicMin(&mir[j], __float_as_uint(d));
                }
            }
        }
    }
}

// Kernel 3: final scalar loss (sqrt applied here; mor!=0 is the or-flag).
__global__ __launch_bounds__(256) void k_final(const unsigned* __restrict__ hp,
                                               const unsigned* __restrict__ hn,
                                               const unsigned* __restrict__ mor,
                                               const unsigned* __restrict__ mir,
                                               const int* __restrict__ epoch_p,
                                               float* __restrict__ out) {
    const int t = threadIdx.x;
    const int i = blockIdx.x * 256 + t;
    const bool eok = (*epoch_p > 50);
    const unsigned morb = mor[i];
    float fhp = sqrtf(__uint_as_float(hp[i]));
    float fhn = sqrtf(__uint_as_float(hn[i]));
    bool use_or = (morb != 0u) && eok;
    float sp = use_or ? sqrtf(__uint_as_float(morb)) : fhp;
    float sn = use_or ? sqrtf(__uint_as_float(mir[i])) : fhn;
    float s = fmaxf(0.f, fhp - fhn + 0.3f) + fmaxf(0.f, sp - fhn + 0.3f) +
              fmaxf(0.f, fhp - sn + 0.3f);
#pragma unroll
    for (int sh = 32; sh > 0; sh >>= 1) s += __shfl_xor(s, sh);
    __shared__ float red[4];
    const int lane = t & 63, wid = t >> 6;
    if (lane == 0) red[wid] = s;
    __syncthreads();
    if (t == 0)
        atomicAdd(out, (red[0] + red[1] + red[2] + red[3]) * (1.f / 4096.f));
}

extern "C" void kernel_launch(void* const* d_in, const int* in_sizes, int n_in,
                              void* d_out, int out_size, void* d_ws, size_t ws_size,
                              hipStream_t stream) {
    const float* X = (const float*)d_in[0];
    const int* ta = (const int*)d_in[1];
    const int* tb = (const int*)d_in[2];
    const int* epoch_p = (const int*)d_in[4];
    float* out = (float*)d_out;

    char* ws = (char*)d_ws;
    unsigned short* Xb = (unsigned short*)ws;  // 16 MB bf16 copy
    size_t off = (size_t)NROW * KDIM * sizeof(unsigned short);
    float* sqv = (float*)(ws + off); off += (size_t)NROW * 4;
    unsigned* hp = (unsigned*)(ws + off); off += (size_t)NROW * 4;
    unsigned* hn = (unsigned*)(ws + off); off += (size_t)NROW * 4;
    unsigned* mor = (unsigned*)(ws + off); off += (size_t)NROW * 4;
    unsigned* mir = (unsigned*)(ws + off); off += (size_t)NROW * 4;

    k_convert<<<NROW, 256, 0, stream>>>(X, Xb, sqv, hp, hn, mor, mir, out);
    k_gemm<<<(NB * (NB + 1)) / 2, 256, 0, stream>>>(Xb, sqv, ta, tb,
                                                    hp, hn, mor, mir);
    k_final<<<NROW / 256, 256, 0, stream>>>(hp, hn, mor, mir, epoch_p, out);
}